// Round 1
// baseline (462.422 us; speedup 1.0000x reference)
//
#include <hip/hip_runtime.h>

// Problem constants: x shape (16, 1, 2048, 2048) fp32.
#define B_  16
#define H_  2048
#define W_  2048
#define HO  (H_ / 2)        // 1024 output rows
#define WO  (W_ / 2)        // 1024 output cols
#define WP  (W_ / 16)       // 128 thread-tiles per row-pair (16 input cols each)
#define NBAND ((size_t)B_ * HO * WO)   // 16,777,216 elems per band

// Native vector type so clang's nontemporal builtins accept it.
typedef float f32x4 __attribute__((ext_vector_type(4)));

// _safe: replace non-finite with 0 (exponent-all-ones test, 2 VALU ops)
__device__ __forceinline__ float safef(float v) {
    unsigned u = __float_as_uint(v);
    return ((u & 0x7f800000u) == 0x7f800000u) ? 0.0f : v;
}

__device__ __forceinline__ f32x4 safe4(f32x4 v) {
    v.x = safef(v.x);
    v.y = safef(v.y);
    v.z = safef(v.z);
    v.w = safef(v.w);
    return v;
}

// One thread: 2x16 input patch -> 8 output cols in each of 4 bands.
// Loads: 8x 16B nontemporal (128 B/lane in flight; 64 B contiguous per row
// per lane -> each wave reads 4 KB contiguous per row). Stores: 8x 16B
// nontemporal (32 B/lane contiguous per band -> 2 KB contiguous per wave
// per band). Zero reuse anywhere -> nt on everything to skip cache alloc.
__global__ __launch_bounds__(256) void dwt2d_haar_kernel(
        const float* __restrict__ x, float* __restrict__ out) {
    unsigned t  = blockIdx.x * 256u + threadIdx.x;   // [0, 16*1024*128)
    unsigned wp = t & (WP - 1);                      // tile index along W
    unsigned h2 = (t >> 7) & (HO - 1);               // output row
    unsigned b  = t >> 17;                           // batch

    size_t in_base = (size_t)b * H_ * W_ + (size_t)(2u * h2) * W_ + 16u * wp;
    const f32x4* top = reinterpret_cast<const f32x4*>(x + in_base);
    const f32x4* bot = reinterpret_cast<const f32x4*>(x + in_base + W_);

    // Issue all 8 loads up front (max MLP), then sanitize.
    f32x4 t0 = __builtin_nontemporal_load(top + 0);
    f32x4 t1 = __builtin_nontemporal_load(top + 1);
    f32x4 t2 = __builtin_nontemporal_load(top + 2);
    f32x4 t3 = __builtin_nontemporal_load(top + 3);
    f32x4 b0 = __builtin_nontemporal_load(bot + 0);
    f32x4 b1 = __builtin_nontemporal_load(bot + 1);
    f32x4 b2 = __builtin_nontemporal_load(bot + 2);
    f32x4 b3 = __builtin_nontemporal_load(bot + 3);
    t0 = safe4(t0); t1 = safe4(t1); t2 = safe4(t2); t3 = safe4(t3);
    b0 = safe4(b0); b1 = safe4(b1); b2 = safe4(b2); b3 = safe4(b3);

    f32x4 ll0, lh0, hl0, hh0;   // output cols 8*wp   .. 8*wp+3
    f32x4 ll1, lh1, hl1, hh1;   // output cols 8*wp+4 .. 8*wp+7

    // 2x2 Haar butterfly: a=top-left b=top-right c=bot-left d=bot-right
#define HAAR(LL, LH, HL, HH, A, Bv, Cv, Dv)      \
    LL = 0.5f * ( (A) + (Bv) + (Cv) + (Dv));     \
    LH = 0.5f * (-(A) + (Bv) - (Cv) + (Dv));     \
    HL = 0.5f * (-(A) - (Bv) + (Cv) + (Dv));     \
    HH = 0.5f * ( (A) - (Bv) - (Cv) + (Dv));

    HAAR(ll0.x, lh0.x, hl0.x, hh0.x, t0.x, t0.y, b0.x, b0.y)
    HAAR(ll0.y, lh0.y, hl0.y, hh0.y, t0.z, t0.w, b0.z, b0.w)
    HAAR(ll0.z, lh0.z, hl0.z, hh0.z, t1.x, t1.y, b1.x, b1.y)
    HAAR(ll0.w, lh0.w, hl0.w, hh0.w, t1.z, t1.w, b1.z, b1.w)

    HAAR(ll1.x, lh1.x, hl1.x, hh1.x, t2.x, t2.y, b2.x, b2.y)
    HAAR(ll1.y, lh1.y, hl1.y, hh1.y, t2.z, t2.w, b2.z, b2.w)
    HAAR(ll1.z, lh1.z, hl1.z, hh1.z, t3.x, t3.y, b3.x, b3.y)
    HAAR(ll1.w, lh1.w, hl1.w, hh1.w, t3.z, t3.w, b3.z, b3.w)
#undef HAAR

    size_t obase = (size_t)b * HO * WO + (size_t)h2 * WO + 8u * wp;

    f32x4* oll = reinterpret_cast<f32x4*>(out + 0 * NBAND + obase);
    f32x4* olh = reinterpret_cast<f32x4*>(out + 1 * NBAND + obase);
    f32x4* ohl = reinterpret_cast<f32x4*>(out + 2 * NBAND + obase);
    f32x4* ohh = reinterpret_cast<f32x4*>(out + 3 * NBAND + obase);

    __builtin_nontemporal_store(ll0, oll + 0);
    __builtin_nontemporal_store(ll1, oll + 1);
    __builtin_nontemporal_store(lh0, olh + 0);
    __builtin_nontemporal_store(lh1, olh + 1);
    __builtin_nontemporal_store(hl0, ohl + 0);
    __builtin_nontemporal_store(hl1, ohl + 1);
    __builtin_nontemporal_store(hh0, ohh + 0);
    __builtin_nontemporal_store(hh1, ohh + 1);
}

extern "C" void kernel_launch(void* const* d_in, const int* in_sizes, int n_in,
                              void* d_out, int out_size, void* d_ws, size_t ws_size,
                              hipStream_t stream) {
    const float* x = (const float*)d_in[0];
    float* out = (float*)d_out;
    // 16 * 1024 * 128 threads = 2,097,152 -> 8192 blocks of 256
    unsigned total_threads = B_ * HO * WP;
    dim3 grid(total_threads / 256u);
    dim3 block(256);
    dwt2d_haar_kernel<<<grid, block, 0, stream>>>(x, out);
}

// Round 2
// 419.308 us; speedup vs baseline: 1.1028x; 1.1028x over previous
//
#include <hip/hip_runtime.h>

// Problem constants: x shape (16, 1, 2048, 2048) fp32.
#define B_  16
#define H_  2048
#define W_  2048
#define HO  (H_ / 2)       // 1024 output rows
#define WO  (W_ / 2)       // 1024 output cols
#define WQ  (W_ / 8)       // 256 quads of 8 input cols (= 4 output cols) per row
#define NBAND ((size_t)B_ * HO * WO)   // 16,777,216 elems per band

// Native vector type so clang's nontemporal builtins accept it.
typedef float f32x4 __attribute__((ext_vector_type(4)));

// _safe: replace non-finite with 0 (exponent-all-ones test, 2 VALU ops)
__device__ __forceinline__ float safef(float v) {
    unsigned u = __float_as_uint(v);
    return ((u & 0x7f800000u) == 0x7f800000u) ? 0.0f : v;
}

__device__ __forceinline__ f32x4 safe4(f32x4 v) {
    v.x = safef(v.x);
    v.y = safef(v.y);
    v.z = safef(v.z);
    v.w = safef(v.w);
    return v;
}

// One thread: 2x8 input patch -> 4 output cols in each of 4 bands.
// Round-0 geometry (every load/store instruction is 16 B/lane with
// CONSECUTIVE lanes at CONSECUTIVE addresses -> 1 KB contiguous per
// instruction) + nontemporal hints (all traffic is touch-once; NT marks
// lines evict-first so the 5 dead streams don't thrash L2 allocation).
__global__ __launch_bounds__(256) void dwt2d_haar_kernel(
        const float* __restrict__ x, float* __restrict__ out) {
    unsigned t  = blockIdx.x * 256u + threadIdx.x;   // [0, 16*1024*256)
    unsigned wq = t & (WQ - 1);                      // quad index along W
    unsigned h2 = (t >> 8) & (HO - 1);               // output row
    unsigned b  = t >> 18;                           // batch

    size_t in_base = (size_t)b * H_ * W_ + (size_t)(2u * h2) * W_ + 8u * wq;
    const f32x4* top = reinterpret_cast<const f32x4*>(x + in_base);
    const f32x4* bot = reinterpret_cast<const f32x4*>(x + in_base + W_);

    f32x4 t0 = __builtin_nontemporal_load(top + 0);
    f32x4 t1 = __builtin_nontemporal_load(top + 1);
    f32x4 b0 = __builtin_nontemporal_load(bot + 0);
    f32x4 b1 = __builtin_nontemporal_load(bot + 1);
    t0 = safe4(t0); t1 = safe4(t1);
    b0 = safe4(b0); b1 = safe4(b1);

    f32x4 ll, lh, hl, hh;

    // 2x2 Haar butterfly: a=top-left b=top-right c=bot-left d=bot-right
#define HAAR(LL, LH, HL, HH, A, Bv, Cv, Dv)      \
    LL = 0.5f * ( (A) + (Bv) + (Cv) + (Dv));     \
    LH = 0.5f * (-(A) + (Bv) - (Cv) + (Dv));     \
    HL = 0.5f * (-(A) - (Bv) + (Cv) + (Dv));     \
    HH = 0.5f * ( (A) - (Bv) - (Cv) + (Dv));

    HAAR(ll.x, lh.x, hl.x, hh.x, t0.x, t0.y, b0.x, b0.y)
    HAAR(ll.y, lh.y, hl.y, hh.y, t0.z, t0.w, b0.z, b0.w)
    HAAR(ll.z, lh.z, hl.z, hh.z, t1.x, t1.y, b1.x, b1.y)
    HAAR(ll.w, lh.w, hl.w, hh.w, t1.z, t1.w, b1.z, b1.w)
#undef HAAR

    size_t obase = (size_t)b * HO * WO + (size_t)h2 * WO + 4u * wq;

    __builtin_nontemporal_store(ll, reinterpret_cast<f32x4*>(out + 0 * NBAND + obase));
    __builtin_nontemporal_store(lh, reinterpret_cast<f32x4*>(out + 1 * NBAND + obase));
    __builtin_nontemporal_store(hl, reinterpret_cast<f32x4*>(out + 2 * NBAND + obase));
    __builtin_nontemporal_store(hh, reinterpret_cast<f32x4*>(out + 3 * NBAND + obase));
}

extern "C" void kernel_launch(void* const* d_in, const int* in_sizes, int n_in,
                              void* d_out, int out_size, void* d_ws, size_t ws_size,
                              hipStream_t stream) {
    const float* x = (const float*)d_in[0];
    float* out = (float*)d_out;
    // 16 * 1024 * 256 threads = 4,194,304 -> 16384 blocks of 256
    unsigned total_threads = B_ * HO * WQ;
    dim3 grid(total_threads / 256u);
    dim3 block(256);
    dwt2d_haar_kernel<<<grid, block, 0, stream>>>(x, out);
}